// Round 15
// baseline (134.540 us; speedup 1.0000x reference)
//
#include <hip/hip_runtime.h>
#include <hip/hip_bf16.h>

typedef __attribute__((ext_vector_type(8)))  short bf16x8;
typedef __attribute__((ext_vector_type(16))) float f32x16;

#define TPB 256
#define SCORE_MARGIN 1e-3f
#define ERR_MARGIN   1e-3f

static __device__ __forceinline__ unsigned short bf16_rne(float v) {
    union { __hip_bfloat16 h; unsigned short u; } cv;
    cv.h = __float2bfloat16(v);
    return cv.u;
}
static __device__ __forceinline__ float bfhi(unsigned u) { return __uint_as_float(u << 16); }
static __device__ __forceinline__ float bflo(unsigned u) { return __uint_as_float(u & 0xffff0000u); }

// ws layout (bytes): [cw: T*32*16][group norms: T*32 (T*8 floats)][remap: T*32*4]
// Class-sorted codebook (norm n in {2,4,6,8,10,12}), classes padded to x4 so
// every C-register group of 4 codewords has equal norm; pads: cw=0, remap=-1,
// all-pad groups norm=-30000. T is padded to a MULTIPLE OF 4 (quad-chain loop).

__global__ __launch_bounds__(256) void e8p_prep(
    const float* __restrict__ grid_part,
    const float* __restrict__ grid_part_norm,
    unsigned char* __restrict__ ws,
    int G, int T)
{
    __shared__ int cnt[6];
    __shared__ int cur[6];
    const int tid = threadIdx.x;
    const int T32 = T * 32;

    unsigned char* cwB  = ws;
    float*         ngB  = (float*)(ws + (size_t)T32 * 16);
    int*           rmB  = (int*)(ws + (size_t)T32 * 16 + (size_t)T * 32);

    for (int c = tid; c < T32; c += 256) {
        uint4 z; z.x = z.y = z.z = z.w = 0u;
        *(uint4*)(cwB + (size_t)c * 16) = z;
        rmB[c] = -1;
    }
    for (int c = tid; c < T * 8; c += 256) ngB[c] = -30000.0f;
    if (tid < 6) { cnt[tid] = 0; cur[tid] = 0; }
    __syncthreads();

    for (int c = tid; c < G; c += 256) {
        const int k = (__float2int_rn(grid_part_norm[c]) >> 1) - 1;
        atomicAdd(&cnt[k], 1);
    }
    __syncthreads();

    int offs[6];
    {
        int o = 0;
#pragma unroll
        for (int k = 0; k < 6; ++k) { offs[k] = o; o += (cnt[k] + 3) & ~3; }
    }

    for (int c = tid; c < G; c += 256) {
        const int k = (__float2int_rn(grid_part_norm[c]) >> 1) - 1;
        const int pos = offs[k] + atomicAdd(&cur[k], 1);
        const float4 g0 = *(const float4*)(grid_part + (size_t)c * 8);
        const float4 g1 = *(const float4*)(grid_part + (size_t)c * 8 + 4);
        uint4 gv;
        gv.x = (unsigned)bf16_rne(g0.x) | ((unsigned)bf16_rne(g0.y) << 16);
        gv.y = (unsigned)bf16_rne(g0.z) | ((unsigned)bf16_rne(g0.w) << 16);
        gv.z = (unsigned)bf16_rne(g1.x) | ((unsigned)bf16_rne(g1.y) << 16);
        gv.w = (unsigned)bf16_rne(g1.z) | ((unsigned)bf16_rne(g1.w) << 16);
        *(uint4*)(cwB + (size_t)pos * 16) = gv;
        rmB[pos] = c;
    }
    __syncthreads();

    // group gi=(t,h,g) covers positions t*32 + 8g + 4h .. +3
    for (int gi = tid; gi < T * 8; gi += 256) {
        const int t = gi >> 3, hh = (gi >> 2) & 1, gg = gi & 3;
        const int p4 = t * 32 + 8 * gg + 4 * hh;
        float v = -30000.0f;
#pragma unroll
        for (int k = 0; k < 6; ++k)
            if (p4 >= offs[k] && p4 < offs[k] + cnt[k]) v = -(float)(k + 1);
        ngB[gi] = v;
    }
}

// ---------------------------------------------------------------------------
// Main kernel, LDS-free (R13/R14 structure, absmax 0.0). R15: QUAD-CHAIN ILP
// — four tiles per iteration into four independent MFMA accumulators sharing
// the loop-invariant B; tracking of chain k overlaps the in-flight MFMAs of
// later chains (R14's ILPx2 gave 84->71us; VALUBusy 47% says half the cycles
// are still stalls). __launch_bounds__(256,2) relaxes the VGPR cap to fit the
// 4 accumulator blocks without spilling (R10 lesson: spills show in
// WRITE_SIZE). Decision logic bit-identical: group tracking + margins + pad
// flags -> inline wave-cooperative fp64 fixup (R2-verified arithmetic).
// Output d_out (float32): [final_vals (N*8) | final_idxs (N)].
// ---------------------------------------------------------------------------
__global__ __launch_bounds__(TPB, 2) void e8p_fused(
    const float* __restrict__ X,
    const float* __restrict__ grid_part,
    const float* __restrict__ grid_part_norm,
    const int*   __restrict__ allcombo_idx,
    const int*   __restrict__ idx_map,
    const unsigned char* __restrict__ ws,
    float* __restrict__ out,
    int N, int G, int T)
{
    const int T32 = T * 32;
    const unsigned char* cwB = ws;
    const float*         ngB = (const float*)(ws + (size_t)T32 * 16);
    const int*           rmB = (const int*)(ws + (size_t)T32 * 16 + (size_t)T * 32);

    const int tid  = threadIdx.x;
    const int lane = tid & 63;
    const int h    = lane >> 5;        // k-half
    const int col  = lane & 31;
    const int wave = blockIdx.x * (TPB / 64) + (tid >> 6);

    const int li     = col >> 1;
    const int branch = col & 1;        // 0: +0.25, 1: -0.25
    const int irow   = wave * 16 + li;
    const int iload  = (irow < N) ? irow : 0;

    float x[8];
    {
        const float4 a = *(const float4*)(X + (size_t)iload * 8);
        const float4 b = *(const float4*)(X + (size_t)iload * 8 + 4);
        x[0]=a.x; x[1]=a.y; x[2]=a.z; x[3]=a.w;
        x[4]=b.x; x[5]=b.y; x[6]=b.z; x[7]=b.w;
    }

    // Branch prep (fp32 signs == fp64 signs)
    float ya[8]; int neg = 0;
    const float sh = branch ? -0.25f : 0.25f;
#pragma unroll
    for (int j = 0; j < 8; ++j) {
        const float yj = x[j] + sh;
        if (yj < 0.0f) neg |= (1 << (7 - j));
        ya[j] = fabsf(yj);
    }
    int mint = neg;
    if (__popc(neg) & 1) { ya[0] = -ya[0]; mint ^= 128; }

    // B fragment: h=0 -> bf16_hi(ya), h=1 -> bf16_lo residual
    bf16x8 bfrag;
#pragma unroll
    for (int j = 0; j < 8; ++j) {
        const unsigned short hi = bf16_rne(ya[j]);
        const unsigned short lo = bf16_rne(ya[j] - bfhi((unsigned)hi));
        bfrag[j] = (short)(h ? lo : hi);
    }

    float best[4], sec[4]; int qt[4];
#pragma unroll
    for (int g = 0; g < 4; ++g) { best[g] = -1e30f; sec[g] = -1e30f; qt[g] = 0; }

    const unsigned char* aptr = cwB + (unsigned)col * 16u;
    const float*         nptr = ngB + h * 4;

    const int P = T >> 2;              // T is a multiple of 4 (padded)
    // prefetch quad 0
    bf16x8 aN[4]; float4 nN[4];
#pragma unroll
    for (int c = 0; c < 4; ++c) {
        aN[c] = *(const bf16x8*)(aptr + (size_t)c * 512);
        nN[c] = *(const float4*)(nptr + (size_t)c * 8);
    }

    const f32x16 czero = {0,0,0,0,0,0,0,0,0,0,0,0,0,0,0,0};
    for (int p = 0; p < P; ++p) {
        bf16x8 af[4]; float4 ng[4];
#pragma unroll
        for (int c = 0; c < 4; ++c) { af[c] = aN[c]; ng[c] = nN[c]; }
        const int pn = (p + 1 < P) ? (p + 1) : p;
#pragma unroll
        for (int c = 0; c < 4; ++c) {
            aN[c] = *(const bf16x8*)(aptr + (size_t)pn * 2048 + (size_t)c * 512);
            nN[c] = *(const float4*)(nptr + (size_t)pn * 32 + (size_t)c * 8);
        }

        // four independent MFMA chains (shared B)
        f32x16 acc[4];
#pragma unroll
        for (int c = 0; c < 4; ++c)
            acc[c] = __builtin_amdgcn_mfma_f32_32x32x16_bf16(af[c], bfrag, czero, 0, 0, 0);

#pragma unroll
        for (int c = 0; c < 4; ++c) {   // tiles 4p..4p+3 in order (first-max-wins)
            const float nga[4] = {ng[c].x, ng[c].y, ng[c].z, ng[c].w};
#pragma unroll
            for (int g = 0; g < 4; ++g) {
                const float m = fmaxf(fmaxf(fmaxf(acc[c][4*g], acc[c][4*g+1]),
                                            acc[c][4*g+2]), acc[c][4*g+3]);
                const float s = m + nga[g];
                const bool gt = s > best[g];
                sec[g]  = __builtin_amdgcn_fmed3f(s, best[g], sec[g]);
                best[g] = fmaxf(best[g], s);
                qt[g]   = gt ? (4 * p + c) : qt[g];
            }
        }
    }

    // ---- reduce 4 group slots -> 1 (lexicographic max-score, min-pos;
    // pos-order ties always flag via ss == bb -> fp64 resolves original order)
    float bb = best[0], ss = sec[0];
    int   ib = (qt[0] << 5) + 4 * h;
#pragma unroll
    for (int g = 1; g < 4; ++g) {
        const int ibg = (qt[g] << 5) + 8 * g + 4 * h;
        const float br = best[g];
        ss = fmaxf(fmaxf(ss, sec[g]), fminf(bb, br));
        const bool take = (br > bb) || ((br == bb) && (ibg < ib));
        bb = fmaxf(bb, br);
        ib = take ? ibg : ib;
    }
    {   // butterfly across the two k-half lane groups (offset 32)
        const float ob = __shfl_xor(bb, 32, 64);
        const float os = __shfl_xor(ss, 32, 64);
        const int   oi = __shfl_xor(ib, 32, 64);
        ss = fmaxf(fmaxf(ss, os), fminf(bb, ob));
        const bool take = (ob > bb) || ((ob == bb) && (oi < ib));
        bb = fmaxf(bb, ob);
        ib = take ? oi : ib;
    }

    // ---- exact fp32 recompute of the winning group's 4 scores
    float hiF[8], loF[8];
#pragma unroll
    for (int j = 0; j < 8; ++j) {
        hiF[j] = bfhi((unsigned)bf16_rne(ya[j]));
        loF[j] = ya[j] - hiF[j];
    }
    const int tW   = ib >> 5;
    const int base = ib & 31;
    const float ngW = ngB[tW * 8 + ((base >> 2) & 1) * 4 + (base >> 3)];
    float sm = -1e30f, sec4 = -1e30f; int km = 0;
#pragma unroll
    for (int k = 0; k < 4; ++k) {
        const uint4 gv = *(const uint4*)(cwB + ((size_t)tW * 32 + base + k) * 16);
        const float g0 = bfhi(gv.x), g1 = bflo(gv.x), g2 = bfhi(gv.y), g3 = bflo(gv.y);
        const float g4 = bfhi(gv.z), g5 = bflo(gv.z), g6 = bfhi(gv.w), g7 = bflo(gv.w);
        float s = ngW;
        s = fmaf(hiF[0], g0, s); s = fmaf(hiF[1], g1, s);
        s = fmaf(hiF[2], g2, s); s = fmaf(hiF[3], g3, s);
        s = fmaf(hiF[4], g4, s); s = fmaf(hiF[5], g5, s);
        s = fmaf(hiF[6], g6, s); s = fmaf(hiF[7], g7, s);
        s = fmaf(loF[0], g0, s); s = fmaf(loF[1], g1, s);
        s = fmaf(loF[2], g2, s); s = fmaf(loF[3], g3, s);
        s = fmaf(loF[4], g4, s); s = fmaf(loF[5], g5, s);
        s = fmaf(loF[6], g6, s); s = fmaf(loF[7], g7, s);
        const bool gt = s > sm;
        sec4 = __builtin_amdgcn_fmed3f(s, sm, sec4);
        sm   = fmaxf(sm, s);
        km   = gt ? k : km;
    }
    int orig = rmB[tW * 32 + base + km];
    const int closeB = ((sm - sec4) < SCORE_MARGIN) | ((bb - ss) < SCORE_MARGIN) |
                       (orig < 0);
    if (orig < 0) orig = 0;                       // keep memory-safe

    // pair swap: even col (plus branch) receives odd col (minus branch)
    const int qO     = __shfl_xor(orig, 1, 64);
    const int closeO = __shfl_xor(closeB, 1, 64);
    const int mintO  = __shfl_xor(mint, 1, 64);

    const bool doEpi = (h == 0) && (branch == 0) && (irow < N);
    bool close = false;
    if (doEpi) {
        const int qP = orig, qM = qO;
        const float* gp_ = grid_part + (size_t)qP * 8;
        const float* gm_ = grid_part + (size_t)qM * 8;
        float vp[8], vm[8];
        float ep2 = 0.0f, em2 = 0.0f;
        bool coin = true;
#pragma unroll
        for (int j = 0; j < 8; ++j) {
            const float maskp = ((mint  >> (7 - j)) & 1) ? -1.0f : 1.0f;
            const float maskm = ((mintO >> (7 - j)) & 1) ? -1.0f : 1.0f;
            vp[j] = gp_[j] * maskp;
            vm[j] = gm_[j] * maskm;
            coin = coin && ((vp[j] - 0.25f) == (vm[j] + 0.25f));  // exact fp32
            const float dpj = (x[j] + 0.25f) - vp[j];
            const float dmj = (x[j] - 0.25f) - vm[j];
            ep2 = fmaf(dpj, dpj, ep2);
            em2 = fmaf(dmj, dmj, em2);
        }
        close = closeB | closeO | (!coin && (fabsf(ep2 - em2) < ERR_MARGIN));
        if (!close) {
            // Coincident -> fp64 ref has pe==me bit-exactly -> which=false.
            const bool which = coin ? false : (ep2 < em2);
            const int rowp = idx_map[mint];
            const int rowm = idx_map[mintO];
            const int pi = allcombo_idx[(size_t)rowp * G + qP];
            const int mi = allcombo_idx[(size_t)rowm * G + qM];
            const float idxval = which ? (float)pi : (float)(mi - 32768);
            float* vout = out + (size_t)irow * 8;
#pragma unroll
            for (int j = 0; j < 8; ++j)
                vout[j] = which ? (vp[j] - 0.25f) : (vm[j] + 0.25f);
            out[(size_t)N * 8 + irow] = idxval;
        }
    }

    // ---- inline fp64 fixup for flagged rows (R2-verified arithmetic) ----
    unsigned long long mb = __ballot(doEpi && close);
    while (mb) {
        const int b = (int)__ffsll(mb) - 1;   // flagged lane: h=0, even col
        mb &= (mb - 1);
        const int liF = b >> 1;
        const int iF  = wave * 16 + liF;
        float xf[8];
#pragma unroll
        for (int j = 0; j < 8; ++j) xf[j] = __shfl(x[j], b, 64);

        double yapF[8], yamF[8];
        int negp = 0, negm = 0;
#pragma unroll
        for (int j = 0; j < 8; ++j) {
            const double xd = (double)xf[j];
            const double ypd = xd + 0.25;
            const double ymd = xd - 0.25;
            if (ypd < 0.0) negp |= (1 << (7 - j));
            if (ymd < 0.0) negm |= (1 << (7 - j));
            yapF[j] = fabs(ypd);
            yamF[j] = fabs(ymd);
        }
        int mintpF = negp, mintmF = negm;
        if (__popc(negp) & 1) { yapF[0] = -yapF[0]; mintpF ^= 128; }
        if (__popc(negm) & 1) { yamF[0] = -yamF[0]; mintmF ^= 128; }

        double bestpF = -1e300, bestmF = -1e300;
        int qpF = 0x7fffffff, qmF = 0x7fffffff;
        for (int j = lane; j < G; j += 64) {
            const float4 g0 = *(const float4*)(grid_part + (size_t)j * 8);
            const float4 g1 = *(const float4*)(grid_part + (size_t)j * 8 + 4);
            const double n = (double)grid_part_norm[j];
            const double t0 = (double)g0.x, t1 = (double)g0.y,
                         t2 = (double)g0.z, t3 = (double)g0.w,
                         t4 = (double)g1.x, t5 = (double)g1.y,
                         t6 = (double)g1.z, t7 = (double)g1.w;
            double dp, dm;
            dp = yapF[0] * t0;           dm = yamF[0] * t0;
            dp = fma(yapF[1], t1, dp);   dm = fma(yamF[1], t1, dm);
            dp = fma(yapF[2], t2, dp);   dm = fma(yamF[2], t2, dm);
            dp = fma(yapF[3], t3, dp);   dm = fma(yamF[3], t3, dm);
            dp = fma(yapF[4], t4, dp);   dm = fma(yamF[4], t4, dm);
            dp = fma(yapF[5], t5, dp);   dm = fma(yamF[5], t5, dm);
            dp = fma(yapF[6], t6, dp);   dm = fma(yamF[6], t6, dm);
            dp = fma(yapF[7], t7, dp);   dm = fma(yamF[7], t7, dm);
            const double sp = 2.0 * dp - n;
            const double sm2 = 2.0 * dm - n;
            if (sp > bestpF) { bestpF = sp; qpF = j; }
            if (sm2 > bestmF) { bestmF = sm2; qmF = j; }
        }
#pragma unroll
        for (int off = 32; off > 0; off >>= 1) {
            double ob = __shfl_xor(bestpF, off, 64);
            int    oq = __shfl_xor(qpF, off, 64);
            if (ob > bestpF || (ob == bestpF && oq < qpF)) { bestpF = ob; qpF = oq; }
            ob = __shfl_xor(bestmF, off, 64);
            oq = __shfl_xor(qmF, off, 64);
            if (ob > bestmF || (ob == bestmF && oq < qmF)) { bestmF = ob; qmF = oq; }
        }
        if (lane == 0) {
            const float* gp_ = grid_part + (size_t)qpF * 8;
            const float* gm_ = grid_part + (size_t)qmF * 8;
            double vp[8], vm[8];
            double ep2 = 0.0, em2 = 0.0;
#pragma unroll
            for (int j = 0; j < 8; ++j) {
                const double maskp = ((mintpF >> (7 - j)) & 1) ? -1.0 : 1.0;
                const double maskm = ((mintmF >> (7 - j)) & 1) ? -1.0 : 1.0;
                vp[j] = (double)gp_[j] * maskp;
                vm[j] = (double)gm_[j] * maskm;
                const double xd = (double)xf[j];
                const double dpj = (xd + 0.25) - vp[j];
                const double dmj = (xd - 0.25) - vm[j];
                ep2 += dpj * dpj;
                em2 += dmj * dmj;
            }
            const double ep = sqrt(ep2), em = sqrt(em2);
            const bool which = ep < em;
            const int rowp = idx_map[mintpF];
            const int rowm = idx_map[mintmF];
            const int pi = allcombo_idx[(size_t)rowp * G + qpF];
            const int mi = allcombo_idx[(size_t)rowm * G + qmF];
            const float idxval = which ? (float)pi : (float)(mi - 32768);
            float* vout = out + (size_t)iF * 8;
#pragma unroll
            for (int j = 0; j < 8; ++j) {
                const double v = which ? (vp[j] - 0.25) : (vm[j] + 0.25);
                vout[j] = (float)v;
            }
            out[(size_t)N * 8 + iF] = idxval;
        }
    }
}

extern "C" void kernel_launch(void* const* d_in, const int* in_sizes, int n_in,
                              void* d_out, int out_size, void* d_ws, size_t ws_size,
                              hipStream_t stream) {
    const float* X    = (const float*)d_in[0];
    const float* gp   = (const float*)d_in[1];
    const float* gn   = (const float*)d_in[2];
    const int*   aci  = (const int*)d_in[3];
    const int*   imap = (const int*)d_in[4];
    // d_in[5] (int_map) and d_in[6] (grid_idx_map) are folded analytically.

    const int N = in_sizes[0] / 8;
    const int G = in_sizes[1] / 8;
    int T = (G + 18 + 31) / 32;                  // class padding <= 6*3 = 18
    T = (T + 3) & ~3;                            // multiple of 4 for quad-chain
    const int blocks = (N + 63) / 64;            // 4 waves x 16 rows per block

    unsigned char* ws = (unsigned char*)d_ws;
    // needs T*32*16 + T*32 + T*32*4 bytes (~31KB) — well under ws_size

    hipLaunchKernelGGL(e8p_prep, dim3(1), dim3(256), 0, stream,
                       gp, gn, ws, G, T);
    hipLaunchKernelGGL(e8p_fused, dim3(blocks), dim3(TPB), 0, stream,
                       X, gp, gn, aci, imap, ws, (float*)d_out, N, G, T);
}

// Round 16
// 132.229 us; speedup vs baseline: 1.0175x; 1.0175x over previous
//
#include <hip/hip_runtime.h>
#include <hip/hip_bf16.h>

typedef __attribute__((ext_vector_type(8)))  short bf16x8;
typedef __attribute__((ext_vector_type(16))) float f32x16;

#define TPB 256
#define SCORE_MARGIN 1e-3f
#define ERR_MARGIN   1e-3f

static __device__ __forceinline__ unsigned short bf16_rne(float v) {
    union { __hip_bfloat16 h; unsigned short u; } cv;
    cv.h = __float2bfloat16(v);
    return cv.u;
}
static __device__ __forceinline__ float bfhi(unsigned u) { return __uint_as_float(u << 16); }
static __device__ __forceinline__ float bflo(unsigned u) { return __uint_as_float(u & 0xffff0000u); }

// ws layout (bytes): [cw: T*32*16][group norms: T*32 (T*8 floats)][remap: T*32*4]
// Class-sorted codebook (norm n in {2,4,6,8,10,12}), classes padded to x4 so
// every C-register group of 4 codewords has equal norm; pads: cw=0, remap=-1,
// all-pad groups norm=-30000. T padded EVEN for the dual-chain loop.

__global__ __launch_bounds__(256) void e8p_prep(
    const float* __restrict__ grid_part,
    const float* __restrict__ grid_part_norm,
    unsigned char* __restrict__ ws,
    int G, int T)
{
    __shared__ int cnt[6];
    __shared__ int cur[6];
    const int tid = threadIdx.x;
    const int T32 = T * 32;

    unsigned char* cwB  = ws;
    float*         ngB  = (float*)(ws + (size_t)T32 * 16);
    int*           rmB  = (int*)(ws + (size_t)T32 * 16 + (size_t)T * 32);

    for (int c = tid; c < T32; c += 256) {
        uint4 z; z.x = z.y = z.z = z.w = 0u;
        *(uint4*)(cwB + (size_t)c * 16) = z;
        rmB[c] = -1;
    }
    for (int c = tid; c < T * 8; c += 256) ngB[c] = -30000.0f;
    if (tid < 6) { cnt[tid] = 0; cur[tid] = 0; }
    __syncthreads();

    for (int c = tid; c < G; c += 256) {
        const int k = (__float2int_rn(grid_part_norm[c]) >> 1) - 1;
        atomicAdd(&cnt[k], 1);
    }
    __syncthreads();

    int offs[6];
    {
        int o = 0;
#pragma unroll
        for (int k = 0; k < 6; ++k) { offs[k] = o; o += (cnt[k] + 3) & ~3; }
    }

    for (int c = tid; c < G; c += 256) {
        const int k = (__float2int_rn(grid_part_norm[c]) >> 1) - 1;
        const int pos = offs[k] + atomicAdd(&cur[k], 1);
        const float4 g0 = *(const float4*)(grid_part + (size_t)c * 8);
        const float4 g1 = *(const float4*)(grid_part + (size_t)c * 8 + 4);
        uint4 gv;
        gv.x = (unsigned)bf16_rne(g0.x) | ((unsigned)bf16_rne(g0.y) << 16);
        gv.y = (unsigned)bf16_rne(g0.z) | ((unsigned)bf16_rne(g0.w) << 16);
        gv.z = (unsigned)bf16_rne(g1.x) | ((unsigned)bf16_rne(g1.y) << 16);
        gv.w = (unsigned)bf16_rne(g1.z) | ((unsigned)bf16_rne(g1.w) << 16);
        *(uint4*)(cwB + (size_t)pos * 16) = gv;
        rmB[pos] = c;
    }
    __syncthreads();

    // group gi=(t,h,g) covers positions t*32 + 8g + 4h .. +3
    for (int gi = tid; gi < T * 8; gi += 256) {
        const int t = gi >> 3, hh = (gi >> 2) & 1, gg = gi & 3;
        const int p4 = t * 32 + 8 * gg + 4 * hh;
        float v = -30000.0f;
#pragma unroll
        for (int k = 0; k < 6; ++k)
            if (p4 >= offs[k] && p4 < offs[k] + cnt[k]) v = -(float)(k + 1);
        ngB[gi] = v;
    }
}

// ---------------------------------------------------------------------------
// Main kernel: R14 dual-chain structure (best: 71us, absmax 0.0) + R16 change:
// the pre-sorted packed codebook is staged into LDS via a LINEAR conflict-free
// copy (no atomics/scatter — sorting already done by e8p_prep). Rationale:
// 27.5KB codebook + streaming X/out traffic exceeds the 32KiB L1, so part of
// the A/norm stream was L2-latency (~200cyc) marginally uncovered by the
// depth-1 prefetch. LDS gives fixed low latency and zero eviction jitter.
// Decision logic bit-identical: group tracking + margins + pad flags ->
// inline wave-cooperative fp64 fixup (R2-verified arithmetic).
// Output d_out (float32): [final_vals (N*8) | final_idxs (N)].
// ---------------------------------------------------------------------------
__global__ __launch_bounds__(TPB, 4) void e8p_fused(
    const float* __restrict__ X,
    const float* __restrict__ grid_part,
    const float* __restrict__ grid_part_norm,
    const int*   __restrict__ allcombo_idx,
    const int*   __restrict__ idx_map,
    const unsigned char* __restrict__ ws,
    float* __restrict__ out,
    int N, int G, int T)
{
    const int T32 = T * 32;
    const unsigned char* cwB = ws;
    const int* rmB = (const int*)(ws + (size_t)T32 * 16 + (size_t)T * 32);

    extern __shared__ __align__(16) unsigned char smem[];
    unsigned char* ldsCW = smem;                          // T*512 bytes
    float*         ldsNG = (float*)(smem + (size_t)T * 512);  // T*8 floats

    const int tid = threadIdx.x;
    // ---- linear conflict-free stage of the pre-sorted codebook ----
    {
        const uint4* src = (const uint4*)ws;
        uint4* dst = (uint4*)smem;
        const int nchunks = T * 32 + T * 2;   // cw (T*32) + norms (T*2) uint4s
        for (int i = tid; i < nchunks; i += TPB) dst[i] = src[i];
    }
    __syncthreads();

    const int lane = tid & 63;
    const int h    = lane >> 5;        // k-half
    const int col  = lane & 31;
    const int wave = blockIdx.x * (TPB / 64) + (tid >> 6);

    const int li     = col >> 1;
    const int branch = col & 1;        // 0: +0.25, 1: -0.25
    const int irow   = wave * 16 + li;
    const int iload  = (irow < N) ? irow : 0;

    float x[8];
    {
        const float4 a = *(const float4*)(X + (size_t)iload * 8);
        const float4 b = *(const float4*)(X + (size_t)iload * 8 + 4);
        x[0]=a.x; x[1]=a.y; x[2]=a.z; x[3]=a.w;
        x[4]=b.x; x[5]=b.y; x[6]=b.z; x[7]=b.w;
    }

    // Branch prep (fp32 signs == fp64 signs)
    float ya[8]; int neg = 0;
    const float sh = branch ? -0.25f : 0.25f;
#pragma unroll
    for (int j = 0; j < 8; ++j) {
        const float yj = x[j] + sh;
        if (yj < 0.0f) neg |= (1 << (7 - j));
        ya[j] = fabsf(yj);
    }
    int mint = neg;
    if (__popc(neg) & 1) { ya[0] = -ya[0]; mint ^= 128; }

    // B fragment: h=0 -> bf16_hi(ya), h=1 -> bf16_lo residual
    bf16x8 bfrag;
#pragma unroll
    for (int j = 0; j < 8; ++j) {
        const unsigned short hi = bf16_rne(ya[j]);
        const unsigned short lo = bf16_rne(ya[j] - bfhi((unsigned)hi));
        bfrag[j] = (short)(h ? lo : hi);
    }

    float best[4], sec[4]; int qt[4];
#pragma unroll
    for (int g = 0; g < 4; ++g) { best[g] = -1e30f; sec[g] = -1e30f; qt[g] = 0; }

    const unsigned char* aptr = ldsCW + (unsigned)col * 16u;
    const float*         nptr = ldsNG + h * 4;

    const int P = T >> 1;              // T is even (padded)
    // prefetch pair 0
    bf16x8 a0N = *(const bf16x8*)(aptr);
    bf16x8 a1N = *(const bf16x8*)(aptr + 512);
    float4 n0N = *(const float4*)(nptr);
    float4 n1N = *(const float4*)(nptr + 8);

    const f32x16 czero = {0,0,0,0,0,0,0,0,0,0,0,0,0,0,0,0};
    for (int p = 0; p < P; ++p) {
        const bf16x8 af0 = a0N, af1 = a1N;
        const float4 ng0 = n0N, ng1 = n1N;
        const int pn = (p + 1 < P) ? (p + 1) : p;
        a0N = *(const bf16x8*)(aptr + (size_t)pn * 1024);
        a1N = *(const bf16x8*)(aptr + (size_t)pn * 1024 + 512);
        n0N = *(const float4*)(nptr + (size_t)pn * 16);
        n1N = *(const float4*)(nptr + (size_t)pn * 16 + 8);

        // two independent MFMA chains (shared B)
        const f32x16 acc0 = __builtin_amdgcn_mfma_f32_32x32x16_bf16(af0, bfrag, czero, 0, 0, 0);
        const f32x16 acc1 = __builtin_amdgcn_mfma_f32_32x32x16_bf16(af1, bfrag, czero, 0, 0, 0);

        const float nga[4] = {ng0.x, ng0.y, ng0.z, ng0.w};
        const float ngb[4] = {ng1.x, ng1.y, ng1.z, ng1.w};
#pragma unroll
        for (int g = 0; g < 4; ++g) {   // tile 2p first (first-max-wins order)
            const float m = fmaxf(fmaxf(fmaxf(acc0[4*g], acc0[4*g+1]), acc0[4*g+2]),
                                  acc0[4*g+3]);
            const float s = m + nga[g];
            const bool gt = s > best[g];
            sec[g]  = __builtin_amdgcn_fmed3f(s, best[g], sec[g]);
            best[g] = fmaxf(best[g], s);
            qt[g]   = gt ? (2 * p) : qt[g];
        }
#pragma unroll
        for (int g = 0; g < 4; ++g) {   // tile 2p+1
            const float m = fmaxf(fmaxf(fmaxf(acc1[4*g], acc1[4*g+1]), acc1[4*g+2]),
                                  acc1[4*g+3]);
            const float s = m + ngb[g];
            const bool gt = s > best[g];
            sec[g]  = __builtin_amdgcn_fmed3f(s, best[g], sec[g]);
            best[g] = fmaxf(best[g], s);
            qt[g]   = gt ? (2 * p + 1) : qt[g];
        }
    }

    // ---- reduce 4 group slots -> 1 (lexicographic max-score, min-pos;
    // pos-order ties always flag via ss == bb -> fp64 resolves original order)
    float bb = best[0], ss = sec[0];
    int   ib = (qt[0] << 5) + 4 * h;
#pragma unroll
    for (int g = 1; g < 4; ++g) {
        const int ibg = (qt[g] << 5) + 8 * g + 4 * h;
        const float br = best[g];
        ss = fmaxf(fmaxf(ss, sec[g]), fminf(bb, br));
        const bool take = (br > bb) || ((br == bb) && (ibg < ib));
        bb = fmaxf(bb, br);
        ib = take ? ibg : ib;
    }
    {   // butterfly across the two k-half lane groups (offset 32)
        const float ob = __shfl_xor(bb, 32, 64);
        const float os = __shfl_xor(ss, 32, 64);
        const int   oi = __shfl_xor(ib, 32, 64);
        ss = fmaxf(fmaxf(ss, os), fminf(bb, ob));
        const bool take = (ob > bb) || ((ob == bb) && (oi < ib));
        bb = fmaxf(bb, ob);
        ib = take ? oi : ib;
    }

    // ---- exact fp32 recompute of the winning group's 4 scores (from LDS)
    float hiF[8], loF[8];
#pragma unroll
    for (int j = 0; j < 8; ++j) {
        hiF[j] = bfhi((unsigned)bf16_rne(ya[j]));
        loF[j] = ya[j] - hiF[j];
    }
    const int tW   = ib >> 5;
    const int base = ib & 31;
    const float ngW = ldsNG[tW * 8 + ((base >> 2) & 1) * 4 + (base >> 3)];
    float sm = -1e30f, sec4 = -1e30f; int km = 0;
#pragma unroll
    for (int k = 0; k < 4; ++k) {
        const uint4 gv = *(const uint4*)(ldsCW + ((size_t)tW * 32 + base + k) * 16);
        const float g0 = bfhi(gv.x), g1 = bflo(gv.x), g2 = bfhi(gv.y), g3 = bflo(gv.y);
        const float g4 = bfhi(gv.z), g5 = bflo(gv.z), g6 = bfhi(gv.w), g7 = bflo(gv.w);
        float s = ngW;
        s = fmaf(hiF[0], g0, s); s = fmaf(hiF[1], g1, s);
        s = fmaf(hiF[2], g2, s); s = fmaf(hiF[3], g3, s);
        s = fmaf(hiF[4], g4, s); s = fmaf(hiF[5], g5, s);
        s = fmaf(hiF[6], g6, s); s = fmaf(hiF[7], g7, s);
        s = fmaf(loF[0], g0, s); s = fmaf(loF[1], g1, s);
        s = fmaf(loF[2], g2, s); s = fmaf(loF[3], g3, s);
        s = fmaf(loF[4], g4, s); s = fmaf(loF[5], g5, s);
        s = fmaf(loF[6], g6, s); s = fmaf(loF[7], g7, s);
        const bool gt = s > sm;
        sec4 = __builtin_amdgcn_fmed3f(s, sm, sec4);
        sm   = fmaxf(sm, s);
        km   = gt ? k : km;
    }
    int orig = rmB[tW * 32 + base + km];
    const int closeB = ((sm - sec4) < SCORE_MARGIN) | ((bb - ss) < SCORE_MARGIN) |
                       (orig < 0);
    if (orig < 0) orig = 0;                       // keep memory-safe

    // pair swap: even col (plus branch) receives odd col (minus branch)
    const int qO     = __shfl_xor(orig, 1, 64);
    const int closeO = __shfl_xor(closeB, 1, 64);
    const int mintO  = __shfl_xor(mint, 1, 64);

    const bool doEpi = (h == 0) && (branch == 0) && (irow < N);
    bool close = false;
    if (doEpi) {
        const int qP = orig, qM = qO;
        const float* gp_ = grid_part + (size_t)qP * 8;
        const float* gm_ = grid_part + (size_t)qM * 8;
        float vp[8], vm[8];
        float ep2 = 0.0f, em2 = 0.0f;
        bool coin = true;
#pragma unroll
        for (int j = 0; j < 8; ++j) {
            const float maskp = ((mint  >> (7 - j)) & 1) ? -1.0f : 1.0f;
            const float maskm = ((mintO >> (7 - j)) & 1) ? -1.0f : 1.0f;
            vp[j] = gp_[j] * maskp;
            vm[j] = gm_[j] * maskm;
            coin = coin && ((vp[j] - 0.25f) == (vm[j] + 0.25f));  // exact fp32
            const float dpj = (x[j] + 0.25f) - vp[j];
            const float dmj = (x[j] - 0.25f) - vm[j];
            ep2 = fmaf(dpj, dpj, ep2);
            em2 = fmaf(dmj, dmj, em2);
        }
        close = closeB | closeO | (!coin && (fabsf(ep2 - em2) < ERR_MARGIN));
        if (!close) {
            // Coincident -> fp64 ref has pe==me bit-exactly -> which=false.
            const bool which = coin ? false : (ep2 < em2);
            const int rowp = idx_map[mint];
            const int rowm = idx_map[mintO];
            const int pi = allcombo_idx[(size_t)rowp * G + qP];
            const int mi = allcombo_idx[(size_t)rowm * G + qM];
            const float idxval = which ? (float)pi : (float)(mi - 32768);
            float* vout = out + (size_t)irow * 8;
#pragma unroll
            for (int j = 0; j < 8; ++j)
                vout[j] = which ? (vp[j] - 0.25f) : (vm[j] + 0.25f);
            out[(size_t)N * 8 + irow] = idxval;
        }
    }

    // ---- inline fp64 fixup for flagged rows (R2-verified arithmetic) ----
    unsigned long long mb = __ballot(doEpi && close);
    while (mb) {
        const int b = (int)__ffsll(mb) - 1;   // flagged lane: h=0, even col
        mb &= (mb - 1);
        const int liF = b >> 1;
        const int iF  = wave * 16 + liF;
        float xf[8];
#pragma unroll
        for (int j = 0; j < 8; ++j) xf[j] = __shfl(x[j], b, 64);

        double yapF[8], yamF[8];
        int negp = 0, negm = 0;
#pragma unroll
        for (int j = 0; j < 8; ++j) {
            const double xd = (double)xf[j];
            const double ypd = xd + 0.25;
            const double ymd = xd - 0.25;
            if (ypd < 0.0) negp |= (1 << (7 - j));
            if (ymd < 0.0) negm |= (1 << (7 - j));
            yapF[j] = fabs(ypd);
            yamF[j] = fabs(ymd);
        }
        int mintpF = negp, mintmF = negm;
        if (__popc(negp) & 1) { yapF[0] = -yapF[0]; mintpF ^= 128; }
        if (__popc(negm) & 1) { yamF[0] = -yamF[0]; mintmF ^= 128; }

        double bestpF = -1e300, bestmF = -1e300;
        int qpF = 0x7fffffff, qmF = 0x7fffffff;
        for (int j = lane; j < G; j += 64) {
            const float4 g0 = *(const float4*)(grid_part + (size_t)j * 8);
            const float4 g1 = *(const float4*)(grid_part + (size_t)j * 8 + 4);
            const double n = (double)grid_part_norm[j];
            const double t0 = (double)g0.x, t1 = (double)g0.y,
                         t2 = (double)g0.z, t3 = (double)g0.w,
                         t4 = (double)g1.x, t5 = (double)g1.y,
                         t6 = (double)g1.z, t7 = (double)g1.w;
            double dp, dm;
            dp = yapF[0] * t0;           dm = yamF[0] * t0;
            dp = fma(yapF[1], t1, dp);   dm = fma(yamF[1], t1, dm);
            dp = fma(yapF[2], t2, dp);   dm = fma(yamF[2], t2, dm);
            dp = fma(yapF[3], t3, dp);   dm = fma(yamF[3], t3, dm);
            dp = fma(yapF[4], t4, dp);   dm = fma(yamF[4], t4, dm);
            dp = fma(yapF[5], t5, dp);   dm = fma(yamF[5], t5, dm);
            dp = fma(yapF[6], t6, dp);   dm = fma(yamF[6], t6, dm);
            dp = fma(yapF[7], t7, dp);   dm = fma(yamF[7], t7, dm);
            const double sp = 2.0 * dp - n;
            const double sm2 = 2.0 * dm - n;
            if (sp > bestpF) { bestpF = sp; qpF = j; }
            if (sm2 > bestmF) { bestmF = sm2; qmF = j; }
        }
#pragma unroll
        for (int off = 32; off > 0; off >>= 1) {
            double ob = __shfl_xor(bestpF, off, 64);
            int    oq = __shfl_xor(qpF, off, 64);
            if (ob > bestpF || (ob == bestpF && oq < qpF)) { bestpF = ob; qpF = oq; }
            ob = __shfl_xor(bestmF, off, 64);
            oq = __shfl_xor(qmF, off, 64);
            if (ob > bestmF || (ob == bestmF && oq < qmF)) { bestmF = ob; qmF = oq; }
        }
        if (lane == 0) {
            const float* gp_ = grid_part + (size_t)qpF * 8;
            const float* gm_ = grid_part + (size_t)qmF * 8;
            double vp[8], vm[8];
            double ep2 = 0.0, em2 = 0.0;
#pragma unroll
            for (int j = 0; j < 8; ++j) {
                const double maskp = ((mintpF >> (7 - j)) & 1) ? -1.0 : 1.0;
                const double maskm = ((mintmF >> (7 - j)) & 1) ? -1.0 : 1.0;
                vp[j] = (double)gp_[j] * maskp;
                vm[j] = (double)gm_[j] * maskm;
                const double xd = (double)xf[j];
                const double dpj = (xd + 0.25) - vp[j];
                const double dmj = (xd - 0.25) - vm[j];
                ep2 += dpj * dpj;
                em2 += dmj * dmj;
            }
            const double ep = sqrt(ep2), em = sqrt(em2);
            const bool which = ep < em;
            const int rowp = idx_map[mintpF];
            const int rowm = idx_map[mintmF];
            const int pi = allcombo_idx[(size_t)rowp * G + qpF];
            const int mi = allcombo_idx[(size_t)rowm * G + qmF];
            const float idxval = which ? (float)pi : (float)(mi - 32768);
            float* vout = out + (size_t)iF * 8;
#pragma unroll
            for (int j = 0; j < 8; ++j) {
                const double v = which ? (vp[j] - 0.25) : (vm[j] + 0.25);
                vout[j] = (float)v;
            }
            out[(size_t)N * 8 + iF] = idxval;
        }
    }
}

extern "C" void kernel_launch(void* const* d_in, const int* in_sizes, int n_in,
                              void* d_out, int out_size, void* d_ws, size_t ws_size,
                              hipStream_t stream) {
    const float* X    = (const float*)d_in[0];
    const float* gp   = (const float*)d_in[1];
    const float* gn   = (const float*)d_in[2];
    const int*   aci  = (const int*)d_in[3];
    const int*   imap = (const int*)d_in[4];
    // d_in[5] (int_map) and d_in[6] (grid_idx_map) are folded analytically.

    const int N = in_sizes[0] / 8;
    const int G = in_sizes[1] / 8;
    int T = (G + 18 + 31) / 32;                  // class padding <= 6*3 = 18
    T += (T & 1);                                // even for the dual-chain loop
    const int blocks = (N + 63) / 64;            // 4 waves x 16 rows per block
    const size_t shmem = (size_t)T * 512 + (size_t)T * 32;  // cw + group norms

    unsigned char* ws = (unsigned char*)d_ws;
    // needs T*32*16 + T*32 + T*32*4 bytes (~31KB) — well under ws_size

    hipLaunchKernelGGL(e8p_prep, dim3(1), dim3(256), 0, stream,
                       gp, gn, ws, G, T);
    hipLaunchKernelGGL(e8p_fused, dim3(blocks), dim3(TPB), shmem, stream,
                       X, gp, gn, aci, imap, ws, (float*)d_out, N, G, T);
}

// Round 17
// 123.507 us; speedup vs baseline: 1.0893x; 1.0706x over previous
//
#include <hip/hip_runtime.h>
#include <hip/hip_bf16.h>

typedef __attribute__((ext_vector_type(8)))  short bf16x8;
typedef __attribute__((ext_vector_type(16))) float f32x16;

#define TPB 256
// R17: margins tightened to the PROVEN error bounds (was 1e-3 blanket):
//  - MFMA score error <= ~1e-5*Sum|ya| + 5e-6 (bf16 hi/lo residual 2^-18|ya|
//    per dim x |g|<=2.5; hi*g, lo*g exact in fp32; accumulate ~2e-6).
//    Dynamic margin M = 5e-5*Sum|ya| + 2e-5 is >=2.5x the 2*eps flip bound.
//  - err^2 fp32 error <= ~1e-5 -> ERR_MARGIN 1e-4 (10x headroom).
// Rationale: at 1e-3, ~14% of rows flagged (typical top-2 gap ~7e-3) and the
// wave-serialized fp64 fixup (~1600cyc/row) dominated the kernel.
#define ERR_MARGIN   1e-4f

static __device__ __forceinline__ unsigned short bf16_rne(float v) {
    union { __hip_bfloat16 h; unsigned short u; } cv;
    cv.h = __float2bfloat16(v);
    return cv.u;
}
static __device__ __forceinline__ float bfhi(unsigned u) { return __uint_as_float(u << 16); }
static __device__ __forceinline__ float bflo(unsigned u) { return __uint_as_float(u & 0xffff0000u); }

// ws layout (bytes): [cw: T*32*16][group norms: T*32 (T*8 floats)][remap: T*32*4]
// Class-sorted codebook (norm n in {2,4,6,8,10,12}), classes padded to x4 so
// every C-register group of 4 codewords has equal norm; pads: cw=0, remap=-1,
// all-pad groups norm=-30000. T padded EVEN for the dual-chain loop.

__global__ __launch_bounds__(256) void e8p_prep(
    const float* __restrict__ grid_part,
    const float* __restrict__ grid_part_norm,
    unsigned char* __restrict__ ws,
    int G, int T)
{
    __shared__ int cnt[6];
    __shared__ int cur[6];
    const int tid = threadIdx.x;
    const int T32 = T * 32;

    unsigned char* cwB  = ws;
    float*         ngB  = (float*)(ws + (size_t)T32 * 16);
    int*           rmB  = (int*)(ws + (size_t)T32 * 16 + (size_t)T * 32);

    for (int c = tid; c < T32; c += 256) {
        uint4 z; z.x = z.y = z.z = z.w = 0u;
        *(uint4*)(cwB + (size_t)c * 16) = z;
        rmB[c] = -1;
    }
    for (int c = tid; c < T * 8; c += 256) ngB[c] = -30000.0f;
    if (tid < 6) { cnt[tid] = 0; cur[tid] = 0; }
    __syncthreads();

    for (int c = tid; c < G; c += 256) {
        const int k = (__float2int_rn(grid_part_norm[c]) >> 1) - 1;
        atomicAdd(&cnt[k], 1);
    }
    __syncthreads();

    int offs[6];
    {
        int o = 0;
#pragma unroll
        for (int k = 0; k < 6; ++k) { offs[k] = o; o += (cnt[k] + 3) & ~3; }
    }

    for (int c = tid; c < G; c += 256) {
        const int k = (__float2int_rn(grid_part_norm[c]) >> 1) - 1;
        const int pos = offs[k] + atomicAdd(&cur[k], 1);
        const float4 g0 = *(const float4*)(grid_part + (size_t)c * 8);
        const float4 g1 = *(const float4*)(grid_part + (size_t)c * 8 + 4);
        uint4 gv;
        gv.x = (unsigned)bf16_rne(g0.x) | ((unsigned)bf16_rne(g0.y) << 16);
        gv.y = (unsigned)bf16_rne(g0.z) | ((unsigned)bf16_rne(g0.w) << 16);
        gv.z = (unsigned)bf16_rne(g1.x) | ((unsigned)bf16_rne(g1.y) << 16);
        gv.w = (unsigned)bf16_rne(g1.z) | ((unsigned)bf16_rne(g1.w) << 16);
        *(uint4*)(cwB + (size_t)pos * 16) = gv;
        rmB[pos] = c;
    }
    __syncthreads();

    // group gi=(t,h,g) covers positions t*32 + 8g + 4h .. +3
    for (int gi = tid; gi < T * 8; gi += 256) {
        const int t = gi >> 3, hh = (gi >> 2) & 1, gg = gi & 3;
        const int p4 = t * 32 + 8 * gg + 4 * hh;
        float v = -30000.0f;
#pragma unroll
        for (int k = 0; k < 6; ++k)
            if (p4 >= offs[k] && p4 < offs[k] + cnt[k]) v = -(float)(k + 1);
        ngB[gi] = v;
    }
}

// ---------------------------------------------------------------------------
// Main kernel: R16 structure (dual-chain MFMA, LDS-staged sorted codebook,
// absmax 0.0) with R17's tightened dynamic margins only. Decision logic
// otherwise bit-identical: group tracking + margins + pad flags -> inline
// wave-cooperative fp64 fixup (R2-verified arithmetic).
// Output d_out (float32): [final_vals (N*8) | final_idxs (N)].
// ---------------------------------------------------------------------------
__global__ __launch_bounds__(TPB, 4) void e8p_fused(
    const float* __restrict__ X,
    const float* __restrict__ grid_part,
    const float* __restrict__ grid_part_norm,
    const int*   __restrict__ allcombo_idx,
    const int*   __restrict__ idx_map,
    const unsigned char* __restrict__ ws,
    float* __restrict__ out,
    int N, int G, int T)
{
    const int T32 = T * 32;
    const int* rmB = (const int*)(ws + (size_t)T32 * 16 + (size_t)T * 32);

    extern __shared__ __align__(16) unsigned char smem[];
    unsigned char* ldsCW = smem;                          // T*512 bytes
    float*         ldsNG = (float*)(smem + (size_t)T * 512);  // T*8 floats

    const int tid = threadIdx.x;
    // ---- linear conflict-free stage of the pre-sorted codebook ----
    {
        const uint4* src = (const uint4*)ws;
        uint4* dst = (uint4*)smem;
        const int nchunks = T * 32 + T * 2;   // cw (T*32) + norms (T*2) uint4s
        for (int i = tid; i < nchunks; i += TPB) dst[i] = src[i];
    }
    __syncthreads();

    const int lane = tid & 63;
    const int h    = lane >> 5;        // k-half
    const int col  = lane & 31;
    const int wave = blockIdx.x * (TPB / 64) + (tid >> 6);

    const int li     = col >> 1;
    const int branch = col & 1;        // 0: +0.25, 1: -0.25
    const int irow   = wave * 16 + li;
    const int iload  = (irow < N) ? irow : 0;

    float x[8];
    {
        const float4 a = *(const float4*)(X + (size_t)iload * 8);
        const float4 b = *(const float4*)(X + (size_t)iload * 8 + 4);
        x[0]=a.x; x[1]=a.y; x[2]=a.z; x[3]=a.w;
        x[4]=b.x; x[5]=b.y; x[6]=b.z; x[7]=b.w;
    }

    // Branch prep (fp32 signs == fp64 signs)
    float ya[8]; int neg = 0;
    float sya = 0.0f;                  // Sum|ya| for the dynamic margin
    const float sh = branch ? -0.25f : 0.25f;
#pragma unroll
    for (int j = 0; j < 8; ++j) {
        const float yj = x[j] + sh;
        if (yj < 0.0f) neg |= (1 << (7 - j));
        ya[j] = fabsf(yj);
        sya += fabsf(yj);
    }
    int mint = neg;
    if (__popc(neg) & 1) { ya[0] = -ya[0]; mint ^= 128; }

    // Dynamic score margin: >=2.5x the provable 2*eps decision-flip bound.
    const float SM = fmaf(5e-5f, sya, 2e-5f);

    // B fragment: h=0 -> bf16_hi(ya), h=1 -> bf16_lo residual
    bf16x8 bfrag;
#pragma unroll
    for (int j = 0; j < 8; ++j) {
        const unsigned short hi = bf16_rne(ya[j]);
        const unsigned short lo = bf16_rne(ya[j] - bfhi((unsigned)hi));
        bfrag[j] = (short)(h ? lo : hi);
    }

    float best[4], sec[4]; int qt[4];
#pragma unroll
    for (int g = 0; g < 4; ++g) { best[g] = -1e30f; sec[g] = -1e30f; qt[g] = 0; }

    const unsigned char* aptr = ldsCW + (unsigned)col * 16u;
    const float*         nptr = ldsNG + h * 4;

    const int P = T >> 1;              // T is even (padded)
    // prefetch pair 0
    bf16x8 a0N = *(const bf16x8*)(aptr);
    bf16x8 a1N = *(const bf16x8*)(aptr + 512);
    float4 n0N = *(const float4*)(nptr);
    float4 n1N = *(const float4*)(nptr + 8);

    const f32x16 czero = {0,0,0,0,0,0,0,0,0,0,0,0,0,0,0,0};
    for (int p = 0; p < P; ++p) {
        const bf16x8 af0 = a0N, af1 = a1N;
        const float4 ng0 = n0N, ng1 = n1N;
        const int pn = (p + 1 < P) ? (p + 1) : p;
        a0N = *(const bf16x8*)(aptr + (size_t)pn * 1024);
        a1N = *(const bf16x8*)(aptr + (size_t)pn * 1024 + 512);
        n0N = *(const float4*)(nptr + (size_t)pn * 16);
        n1N = *(const float4*)(nptr + (size_t)pn * 16 + 8);

        // two independent MFMA chains (shared B)
        const f32x16 acc0 = __builtin_amdgcn_mfma_f32_32x32x16_bf16(af0, bfrag, czero, 0, 0, 0);
        const f32x16 acc1 = __builtin_amdgcn_mfma_f32_32x32x16_bf16(af1, bfrag, czero, 0, 0, 0);

        const float nga[4] = {ng0.x, ng0.y, ng0.z, ng0.w};
        const float ngb[4] = {ng1.x, ng1.y, ng1.z, ng1.w};
#pragma unroll
        for (int g = 0; g < 4; ++g) {   // tile 2p first (first-max-wins order)
            const float m = fmaxf(fmaxf(fmaxf(acc0[4*g], acc0[4*g+1]), acc0[4*g+2]),
                                  acc0[4*g+3]);
            const float s = m + nga[g];
            const bool gt = s > best[g];
            sec[g]  = __builtin_amdgcn_fmed3f(s, best[g], sec[g]);
            best[g] = fmaxf(best[g], s);
            qt[g]   = gt ? (2 * p) : qt[g];
        }
#pragma unroll
        for (int g = 0; g < 4; ++g) {   // tile 2p+1
            const float m = fmaxf(fmaxf(fmaxf(acc1[4*g], acc1[4*g+1]), acc1[4*g+2]),
                                  acc1[4*g+3]);
            const float s = m + ngb[g];
            const bool gt = s > best[g];
            sec[g]  = __builtin_amdgcn_fmed3f(s, best[g], sec[g]);
            best[g] = fmaxf(best[g], s);
            qt[g]   = gt ? (2 * p + 1) : qt[g];
        }
    }

    // ---- reduce 4 group slots -> 1 (lexicographic max-score, min-pos;
    // pos-order ties always flag via ss == bb -> fp64 resolves original order)
    float bb = best[0], ss = sec[0];
    int   ib = (qt[0] << 5) + 4 * h;
#pragma unroll
    for (int g = 1; g < 4; ++g) {
        const int ibg = (qt[g] << 5) + 8 * g + 4 * h;
        const float br = best[g];
        ss = fmaxf(fmaxf(ss, sec[g]), fminf(bb, br));
        const bool take = (br > bb) || ((br == bb) && (ibg < ib));
        bb = fmaxf(bb, br);
        ib = take ? ibg : ib;
    }
    {   // butterfly across the two k-half lane groups (offset 32)
        const float ob = __shfl_xor(bb, 32, 64);
        const float os = __shfl_xor(ss, 32, 64);
        const int   oi = __shfl_xor(ib, 32, 64);
        ss = fmaxf(fmaxf(ss, os), fminf(bb, ob));
        const bool take = (ob > bb) || ((ob == bb) && (oi < ib));
        bb = fmaxf(bb, ob);
        ib = take ? oi : ib;
    }

    // ---- exact fp32 recompute of the winning group's 4 scores (from LDS;
    // loF = ya - hiF is Sterbenz-exact, so only fma rounding here)
    float hiF[8], loF[8];
#pragma unroll
    for (int j = 0; j < 8; ++j) {
        hiF[j] = bfhi((unsigned)bf16_rne(ya[j]));
        loF[j] = ya[j] - hiF[j];
    }
    const int tW   = ib >> 5;
    const int base = ib & 31;
    const float ngW = ldsNG[tW * 8 + ((base >> 2) & 1) * 4 + (base >> 3)];
    float sm = -1e30f, sec4 = -1e30f; int km = 0;
#pragma unroll
    for (int k = 0; k < 4; ++k) {
        const uint4 gv = *(const uint4*)(ldsCW + ((size_t)tW * 32 + base + k) * 16);
        const float g0 = bfhi(gv.x), g1 = bflo(gv.x), g2 = bfhi(gv.y), g3 = bflo(gv.y);
        const float g4 = bfhi(gv.z), g5 = bflo(gv.z), g6 = bfhi(gv.w), g7 = bflo(gv.w);
        float s = ngW;
        s = fmaf(hiF[0], g0, s); s = fmaf(hiF[1], g1, s);
        s = fmaf(hiF[2], g2, s); s = fmaf(hiF[3], g3, s);
        s = fmaf(hiF[4], g4, s); s = fmaf(hiF[5], g5, s);
        s = fmaf(hiF[6], g6, s); s = fmaf(hiF[7], g7, s);
        s = fmaf(loF[0], g0, s); s = fmaf(loF[1], g1, s);
        s = fmaf(loF[2], g2, s); s = fmaf(loF[3], g3, s);
        s = fmaf(loF[4], g4, s); s = fmaf(loF[5], g5, s);
        s = fmaf(loF[6], g6, s); s = fmaf(loF[7], g7, s);
        const bool gt = s > sm;
        sec4 = __builtin_amdgcn_fmed3f(s, sm, sec4);
        sm   = fmaxf(sm, s);
        km   = gt ? k : km;
    }
    int orig = rmB[tW * 32 + base + km];
    const int closeB = ((sm - sec4) < SM) | ((bb - ss) < SM) | (orig < 0);
    if (orig < 0) orig = 0;                       // keep memory-safe

    // pair swap: even col (plus branch) receives odd col (minus branch)
    const int qO     = __shfl_xor(orig, 1, 64);
    const int closeO = __shfl_xor(closeB, 1, 64);
    const int mintO  = __shfl_xor(mint, 1, 64);

    const bool doEpi = (h == 0) && (branch == 0) && (irow < N);
    bool close = false;
    if (doEpi) {
        const int qP = orig, qM = qO;
        const float* gp_ = grid_part + (size_t)qP * 8;
        const float* gm_ = grid_part + (size_t)qM * 8;
        float vp[8], vm[8];
        float ep2 = 0.0f, em2 = 0.0f;
        bool coin = true;
#pragma unroll
        for (int j = 0; j < 8; ++j) {
            const float maskp = ((mint  >> (7 - j)) & 1) ? -1.0f : 1.0f;
            const float maskm = ((mintO >> (7 - j)) & 1) ? -1.0f : 1.0f;
            vp[j] = gp_[j] * maskp;
            vm[j] = gm_[j] * maskm;
            coin = coin && ((vp[j] - 0.25f) == (vm[j] + 0.25f));  // exact fp32
            const float dpj = (x[j] + 0.25f) - vp[j];
            const float dmj = (x[j] - 0.25f) - vm[j];
            ep2 = fmaf(dpj, dpj, ep2);
            em2 = fmaf(dmj, dmj, em2);
        }
        close = closeB | closeO | (!coin && (fabsf(ep2 - em2) < ERR_MARGIN));
        if (!close) {
            // Coincident -> fp64 ref has pe==me bit-exactly -> which=false.
            const bool which = coin ? false : (ep2 < em2);
            const int rowp = idx_map[mint];
            const int rowm = idx_map[mintO];
            const int pi = allcombo_idx[(size_t)rowp * G + qP];
            const int mi = allcombo_idx[(size_t)rowm * G + qM];
            const float idxval = which ? (float)pi : (float)(mi - 32768);
            float* vout = out + (size_t)irow * 8;
#pragma unroll
            for (int j = 0; j < 8; ++j)
                vout[j] = which ? (vp[j] - 0.25f) : (vm[j] + 0.25f);
            out[(size_t)N * 8 + irow] = idxval;
        }
    }

    // ---- inline fp64 fixup for flagged rows (R2-verified arithmetic) ----
    unsigned long long mb = __ballot(doEpi && close);
    while (mb) {
        const int b = (int)__ffsll(mb) - 1;   // flagged lane: h=0, even col
        mb &= (mb - 1);
        const int liF = b >> 1;
        const int iF  = wave * 16 + liF;
        float xf[8];
#pragma unroll
        for (int j = 0; j < 8; ++j) xf[j] = __shfl(x[j], b, 64);

        double yapF[8], yamF[8];
        int negp = 0, negm = 0;
#pragma unroll
        for (int j = 0; j < 8; ++j) {
            const double xd = (double)xf[j];
            const double ypd = xd + 0.25;
            const double ymd = xd - 0.25;
            if (ypd < 0.0) negp |= (1 << (7 - j));
            if (ymd < 0.0) negm |= (1 << (7 - j));
            yapF[j] = fabs(ypd);
            yamF[j] = fabs(ymd);
        }
        int mintpF = negp, mintmF = negm;
        if (__popc(negp) & 1) { yapF[0] = -yapF[0]; mintpF ^= 128; }
        if (__popc(negm) & 1) { yamF[0] = -yamF[0]; mintmF ^= 128; }

        double bestpF = -1e300, bestmF = -1e300;
        int qpF = 0x7fffffff, qmF = 0x7fffffff;
        for (int j = lane; j < G; j += 64) {
            const float4 g0 = *(const float4*)(grid_part + (size_t)j * 8);
            const float4 g1 = *(const float4*)(grid_part + (size_t)j * 8 + 4);
            const double n = (double)grid_part_norm[j];
            const double t0 = (double)g0.x, t1 = (double)g0.y,
                         t2 = (double)g0.z, t3 = (double)g0.w,
                         t4 = (double)g1.x, t5 = (double)g1.y,
                         t6 = (double)g1.z, t7 = (double)g1.w;
            double dp, dm;
            dp = yapF[0] * t0;           dm = yamF[0] * t0;
            dp = fma(yapF[1], t1, dp);   dm = fma(yamF[1], t1, dm);
            dp = fma(yapF[2], t2, dp);   dm = fma(yamF[2], t2, dm);
            dp = fma(yapF[3], t3, dp);   dm = fma(yamF[3], t3, dm);
            dp = fma(yapF[4], t4, dp);   dm = fma(yamF[4], t4, dm);
            dp = fma(yapF[5], t5, dp);   dm = fma(yamF[5], t5, dm);
            dp = fma(yapF[6], t6, dp);   dm = fma(yamF[6], t6, dm);
            dp = fma(yapF[7], t7, dp);   dm = fma(yamF[7], t7, dm);
            const double sp = 2.0 * dp - n;
            const double sm2 = 2.0 * dm - n;
            if (sp > bestpF) { bestpF = sp; qpF = j; }
            if (sm2 > bestmF) { bestmF = sm2; qmF = j; }
        }
#pragma unroll
        for (int off = 32; off > 0; off >>= 1) {
            double ob = __shfl_xor(bestpF, off, 64);
            int    oq = __shfl_xor(qpF, off, 64);
            if (ob > bestpF || (ob == bestpF && oq < qpF)) { bestpF = ob; qpF = oq; }
            ob = __shfl_xor(bestmF, off, 64);
            oq = __shfl_xor(qmF, off, 64);
            if (ob > bestmF || (ob == bestmF && oq < qmF)) { bestmF = ob; qmF = oq; }
        }
        if (lane == 0) {
            const float* gp_ = grid_part + (size_t)qpF * 8;
            const float* gm_ = grid_part + (size_t)qmF * 8;
            double vp[8], vm[8];
            double ep2 = 0.0, em2 = 0.0;
#pragma unroll
            for (int j = 0; j < 8; ++j) {
                const double maskp = ((mintpF >> (7 - j)) & 1) ? -1.0 : 1.0;
                const double maskm = ((mintmF >> (7 - j)) & 1) ? -1.0 : 1.0;
                vp[j] = (double)gp_[j] * maskp;
                vm[j] = (double)gm_[j] * maskm;
                const double xd = (double)xf[j];
                const double dpj = (xd + 0.25) - vp[j];
                const double dmj = (xd - 0.25) - vm[j];
                ep2 += dpj * dpj;
                em2 += dmj * dmj;
            }
            const double ep = sqrt(ep2), em = sqrt(em2);
            const bool which = ep < em;
            const int rowp = idx_map[mintpF];
            const int rowm = idx_map[mintmF];
            const int pi = allcombo_idx[(size_t)rowp * G + qpF];
            const int mi = allcombo_idx[(size_t)rowm * G + qmF];
            const float idxval = which ? (float)pi : (float)(mi - 32768);
            float* vout = out + (size_t)iF * 8;
#pragma unroll
            for (int j = 0; j < 8; ++j) {
                const double v = which ? (vp[j] - 0.25) : (vm[j] + 0.25);
                vout[j] = (float)v;
            }
            out[(size_t)N * 8 + iF] = idxval;
        }
    }
}

extern "C" void kernel_launch(void* const* d_in, const int* in_sizes, int n_in,
                              void* d_out, int out_size, void* d_ws, size_t ws_size,
                              hipStream_t stream) {
    const float* X    = (const float*)d_in[0];
    const float* gp   = (const float*)d_in[1];
    const float* gn   = (const float*)d_in[2];
    const int*   aci  = (const int*)d_in[3];
    const int*   imap = (const int*)d_in[4];
    // d_in[5] (int_map) and d_in[6] (grid_idx_map) are folded analytically.

    const int N = in_sizes[0] / 8;
    const int G = in_sizes[1] / 8;
    int T = (G + 18 + 31) / 32;                  // class padding <= 6*3 = 18
    T += (T & 1);                                // even for the dual-chain loop
    const int blocks = (N + 63) / 64;            // 4 waves x 16 rows per block
    const size_t shmem = (size_t)T * 512 + (size_t)T * 32;  // cw + group norms

    unsigned char* ws = (unsigned char*)d_ws;
    // needs T*32*16 + T*32 + T*32*4 bytes (~31KB) — well under ws_size

    hipLaunchKernelGGL(e8p_prep, dim3(1), dim3(256), 0, stream,
                       gp, gn, ws, G, T);
    hipLaunchKernelGGL(e8p_fused, dim3(blocks), dim3(TPB), shmem, stream,
                       X, gp, gn, aci, imap, ws, (float*)d_out, N, G, T);
}